// Round 14
// baseline (753.408 us; speedup 1.0000x reference)
//
#include <hip/hip_runtime.h>

#define H  512
#define NN 10000
#define SS 20
#define VV 100000
#define EE 100000

typedef __bf16 bf16x8 __attribute__((ext_vector_type(8)));
typedef float  f32x4  __attribute__((ext_vector_type(4)));

__device__ __forceinline__ unsigned short f2bf(float f) {
  unsigned u = __builtin_bit_cast(unsigned, f);
  u += 0x7FFFu + ((u >> 16) & 1u);
  return (unsigned short)(u >> 16);
}
__device__ __forceinline__ float bflo(int x) {
  return __builtin_bit_cast(float, (unsigned)x << 16);
}
__device__ __forceinline__ float bfhi(int x) {
  return __builtin_bit_cast(float, (unsigned)x & 0xFFFF0000u);
}
__device__ __forceinline__ float sigm(float x) { return 1.f / (1.f + __expf(-x)); }

// bf16 packing (kept for out2_kernel staging)
__device__ __forceinline__ unsigned cpk(float lo, float hi) {
  unsigned r;
  asm("v_cvt_pk_bf16_f32 %0, %1, %2" : "=v"(r) : "v"(lo), "v"(hi));
  return r;
}
__device__ __forceinline__ void cvt_store8(unsigned short* dst, float4 a, float4 b) {
  int4 v;
  v.x = (int)cpk(a.x, a.y); v.y = (int)cpk(a.z, a.w);
  v.z = (int)cpk(b.x, b.y); v.w = (int)cpk(b.z, b.w);
  *(int4*)dst = v;
}

// 8 f32 -> 8 fp8 (OCP e4m3 on gfx950) packed in a uint2 (4 VALU ops).
__device__ __forceinline__ uint2 cvt8_fp8(float4 a, float4 b) {
  int x = __builtin_amdgcn_cvt_pk_fp8_f32(a.x, a.y, 0, false);
  x = __builtin_amdgcn_cvt_pk_fp8_f32(a.z, a.w, x, true);
  int y = __builtin_amdgcn_cvt_pk_fp8_f32(b.x, b.y, 0, false);
  y = __builtin_amdgcn_cvt_pk_fp8_f32(b.z, b.w, y, true);
  uint2 r; r.x = (unsigned)x; r.y = (unsigned)y; return r;
}

// async global -> LDS DMA, 16B/lane, zero VGPR landing. LDS dest must be
// wave-uniform (HW adds lane*16); global src is per-lane.
typedef __attribute__((address_space(1))) const unsigned int gu32_t;
typedef __attribute__((address_space(3))) unsigned int lu32_t;
__device__ __forceinline__ void dma16(const float* g, float* l) {
  __builtin_amdgcn_global_load_lds((gu32_t*)g, (lu32_t*)l, 16, 0, 0);
}

// ---------------- fused gather + GEMM + GRU scan (persistent-B, fp8) --------
// R14: 3 waves/SIMD AND no spill via global_load_lds staging.
// Design matrix so far: R12 fp8@(256,3)+spill = 596us; R13 fp8@(256,2)
// no-spill = 620us -> occupancy-3 wins, spill costs ~25-50us. The 24 f32
// prefetch regs were what overflowed the 170/wave cap; DMA staging removes
// them ENTIRELY (f32 gather lands in LDS, not VGPRs): ~130 regs/wave.
//   body(kc): [vmcnt(0) lgkm(0); s_barrier] ; issue 5 DMA (chunk kc+2 ->
//             fbuf[kc&1]) ; cvt chunk kc+1 (fbuf[(kc+1)&1] -> As[(kc+1)&1],
//             12 cvt_pk + swizzled b64 writes) ; MFMA chunk kc <- As[kc&1]
// Safety: fbuf[kc&1]'s previous reader = body kc-1's cvt -> retired by body
// kc's barrier. As[x]: write body kc, read body kc+1, rewrite body kc+2 --
// each transition straddles a barrier (holds across the ng boundary: chunk
// 8n+c keeps parity c). vmcnt(0) drains 1-body-old DMAs (cheap). DMA row
// mapping: lane of (wave w, inst j) fetches walk row LMAP((w*5+j)*4+s4) ->
// fbuf linear row (w*5+j)*4+s4 (LDS dest uniform: HW adds lane*16).
// fp8 swizzle f(ar)=(ar>>1)&7 unchanged (R10-verified conflict-free).
// LDS: 2x20KB f32 + 2x5KB fp8 = 51200B -> exactly 3 blocks/CU.
// Grid 16cg x 48sb = 768 = 3/CU, __launch_bounds__(256,3).
// XCD swizzle (bijective, all 16 cg of an sb on one XCD): hwid = by*16+bx;
// j = hwid>>3; cg = j&15, sb = (hwid&7)*6 + (j>>4).
__launch_bounds__(256, 3)
__global__ void gru_fused(const float* __restrict__ emb,
                          const float* __restrict__ W_ir,
                          const float* __restrict__ W_iz,
                          const float* __restrict__ b_ir,
                          const float* __restrict__ b_iz,
                          const int* __restrict__ walk,
                          unsigned short* __restrict__ hnb) {
  __shared__ __align__(16) float fbuf[2][80 * 64];        // f32 DMA staging
  __shared__ __align__(16) unsigned char As[2][80 * 64];  // fp8 tiles, 64B rows

  const int tid = threadIdx.x;
  const int w = tid >> 6, lane = tid & 63;
  const int r = lane & 15, q = lane >> 4;

  // XCD-aware remap (see header comment)
  const int hwid = blockIdx.y * 16 + blockIdx.x;
  const int j = hwid >> 3;
  const int cg = j & 15;
  const int sb = (hwid & 7) * 6 + (j >> 4);
  const int c0 = cg * 32;

  // ---- persistent B fragments: 2 tiles x 16 k-steps x 8 fp8 = 64 VGPRs ----
  const int ly = r & 1;                       // layer of this lane's columns
  const int cch = c0 + 8 * w + (r >> 1);      // channel of this lane's columns
  long long barr[2][16];
  float bias2[2];
  #pragma unroll
  for (int t = 0; t < 2; ++t) {               // t: 0 = h (W_ir), 1 = z (W_iz)
    const float* wrow = (t ? W_iz : W_ir) + (long)ly * H * H + (long)cch * H;
    #pragma unroll
    for (int u = 0; u < 16; ++u) {
      const float* s = wrow + u * 32 + q * 8;
      uint2 v = cvt8_fp8(*(const float4*)s, *(const float4*)(s + 4));
      barr[t][u] = __builtin_bit_cast(long long, v);
    }
    bias2[t] = (t ? b_iz : b_ir)[ly * H + cch];
  }

  // ---- DMA role: lane of (w, inst j) owns fbuf row (w*5+j)*4 + s4 ----------
  // LMAP(m)=20*((m>>2)&3)+4*(m>>4)+(m&3); m=(w*5+j)*4+s4 ->
  // L[j] = 20*((w5+j)&3) + 4*((w5+j)>>2) + s4.
  const int s4 = lane >> 4;
  const int c4 = (lane & 15) * 4;             // f32 col offset within chunk
  int L[5];
  #pragma unroll
  for (int jj = 0; jj < 5; ++jj) {
    const int t5 = w * 5 + jj;
    L[jj] = 20 * (t5 & 3) + 4 * (t5 >> 2) + s4;
  }
  const int dmaw = w * 1280;                  // wave-uniform fbuf base (f32)

  // ---- cvt role: thread -> rows {row0, +32, +64 (tid<128)} -----------------
  // SWZ(m)=m*64+((g0^((m>>1)&7))*8): SWZ(m+32)=+2048, SWZ(m+64)=+4096 (bytes)
  const int row0 = tid >> 3, g0 = tid & 7;
  const bool has2 = (tid < 128);              // wave-uniform (waves 0,1)
  const int sw0 = row0 * 64 + ((g0 ^ ((row0 >> 1) & 7)) * 8);
  const int fo0 = row0 * 64 + g0 * 8;         // f32 read offset (floats)

  const int ngA = (2500 * sb) / 48;
  const int ngB = (2500 * (sb + 1)) / 48;

  int ncur[5];
  {
    const int* wp = walk + ngA * 80;
    #pragma unroll
    for (int jj = 0; jj < 5; ++jj) {
      int v = wp[L[jj]]; v = ((unsigned)v < VV) ? v : 0;
      ncur[jj] = v * H;
    }
  }

  // ---- prologue: DMA chunks 0,1; cvt chunk 0 -> As[0] ----------------------
  {
    float* fb0 = &fbuf[0][0] + dmaw;
    float* fb1 = &fbuf[1][0] + dmaw;
    #pragma unroll
    for (int jj = 0; jj < 5; ++jj)
      dma16(emb + ncur[jj] + c4, fb0 + jj * 256);
    #pragma unroll
    for (int jj = 0; jj < 5; ++jj)
      dma16(emb + ncur[jj] + 64 + c4, fb1 + jj * 256);
    // chunk0 done (chunk1's 5 DMAs remain in flight); publish to all waves
    asm volatile("s_waitcnt vmcnt(5) lgkmcnt(0)\n\ts_barrier" ::: "memory");
    const float* fs = &fbuf[0][0];
    unsigned char* An = &As[0][0];
    const float* p = fs + fo0;
    *(uint2*)(An + sw0) = cvt8_fp8(*(const float4*)p, *(const float4*)(p + 4));
    p += 2048;
    *(uint2*)(An + sw0 + 2048) = cvt8_fp8(*(const float4*)p, *(const float4*)(p + 4));
    if (has2) {
      p += 2048;
      *(uint2*)(An + sw0 + 4096) = cvt8_fp8(*(const float4*)p, *(const float4*)(p + 4));
    }
  }

  f32x4 acc[5][2];
  const f32x4 fz = {0.f, 0.f, 0.f, 0.f};

  for (int ng = ngA; ng < ngB; ++ng) {
    #pragma unroll
    for (int mt = 0; mt < 5; ++mt)
      #pragma unroll
      for (int t = 0; t < 2; ++t) acc[mt][t] = fz;

    const int ngn = (ng + 1 < ngB) ? ng + 1 : ng;   // clamped walk prefetch
    int nnxt[5];
    {
      const int* wp = walk + ngn * 80;
      #pragma unroll
      for (int jj = 0; jj < 5; ++jj) {
        int v = wp[L[jj]]; v = ((unsigned)v < VV) ? v : 0;
        nnxt[jj] = v * H;
      }
    }

    #pragma unroll
    for (int kc = 0; kc < 8; ++kc) {
      // (a) drain 1-body-old DMAs (chunk kc+1) + publish fp8(kc+1)'s writes
      //     from last body; retires cvt-reads of fbuf[kc&1] (body kc-1).
      asm volatile("s_waitcnt vmcnt(0) lgkmcnt(0)\n\ts_barrier" ::: "memory");

      // (b) issue 5 DMA: chunk kc+2 -> fbuf[kc&1] (wraps into next ng)
      {
        const int cix = kc + 2;                     // 2..9, compile-time
        const int off = (cix & 7) * 64;
        float* fb = &fbuf[kc & 1][0] + dmaw;
        #pragma unroll
        for (int jj = 0; jj < 5; ++jj) {
          const int nb = (cix < 8) ? ncur[jj] : nnxt[jj];
          dma16(emb + nb + off + c4, fb + jj * 256);
        }
      }

      // (c) cvt chunk kc+1: fbuf[(kc+1)&1] (DMA'd last body) -> As[(kc+1)&1]
      {
        const float* fs = &fbuf[(kc + 1) & 1][0];
        unsigned char* An = &As[(kc + 1) & 1][0];
        const float* p = fs + fo0;
        *(uint2*)(An + sw0) = cvt8_fp8(*(const float4*)p, *(const float4*)(p + 4));
        p += 2048;
        *(uint2*)(An + sw0 + 2048) = cvt8_fp8(*(const float4*)p, *(const float4*)(p + 4));
        if (has2) {
          p += 2048;
          *(uint2*)(An + sw0 + 4096) = cvt8_fp8(*(const float4*)p, *(const float4*)(p + 4));
        }
      }

      // (d) frag reads + MFMA for chunk kc (As[kc&1], published by (a))
      const unsigned char* Ab = &As[kc & 1][0];
      #pragma unroll
      for (int ks = 0; ks < 2; ++ks) {
        const int sx = r * 64 + (((ks * 4 + q) ^ (r >> 1)) * 8);
        long long a[5];
        #pragma unroll
        for (int mt = 0; mt < 5; ++mt)
          a[mt] = *(const long long*)(Ab + mt * 1024 + sx);
        #pragma unroll
        for (int mt = 0; mt < 5; ++mt)
          #pragma unroll
          for (int t = 0; t < 2; ++t)
            acc[mt][t] = __builtin_amdgcn_mfma_f32_16x16x32_fp8_fp8(
                a[mt], barr[t][kc * 2 + ks], acc[mt][t], 0, 0, 0);
      }
    }

    // ---- epilogue: pure lane-local scan; direct hn store (no barrier) ------
    {
      float hn1 = 0.f, a2 = 1.f, b2 = 0.f;
      #pragma unroll
      for (int s = 0; s < 20; ++s) {
        const float yh = acc[s >> 2][0][s & 3] + bias2[0];
        const float yz = acc[s >> 2][1][s & 3] + bias2[1];
        const float z = sigm(yz);
        hn1 += z * (yh - hn1);     // layer-1 direct scan (valid on ly==0 lanes)
        a2 *= (1.f - z);           // layer-2 affine (valid on ly==1 lanes)
        b2 += z * (yh - b2);
      }
      const float u2 = __shfl_xor(hn1, 1);    // ly1 lane gets ly0's hn1
      if (ly == 1)
        hnb[(long)(ng * 4 + q) * 1024 + cch] = f2bf(a2 * u2 + b2);
    }
    #pragma unroll
    for (int jj = 0; jj < 5; ++jj) ncur[jj] = nnxt[jj];
  }
}

// ------- score slot (raw sigmoid) = sigmoid(hn . lin_w + lin_b) -------------
__global__ void score_kernel(const unsigned short* __restrict__ hnb,
                             const float* __restrict__ lin_w,
                             const float* __restrict__ lin_b,
                             float* __restrict__ R) {
  int tid = threadIdx.x;
  int wv = tid >> 6, lane = tid & 63;
  int node = blockIdx.x * 4 + wv;
  int k = lane * 8;
  int4 hv = *(const int4*)(hnb + (long)node * 1024 + k);
  float4 w0 = *(const float4*)(lin_w + k);
  float4 w1 = *(const float4*)(lin_w + k + 4);
  float s = bflo(hv.x) * w0.x + bfhi(hv.x) * w0.y + bflo(hv.y) * w0.z + bfhi(hv.y) * w0.w
          + bflo(hv.z) * w1.x + bfhi(hv.z) * w1.y + bflo(hv.w) * w1.z + bfhi(hv.w) * w1.w;
  #pragma unroll
  for (int off = 32; off > 0; off >>= 1) s += __shfl_down(s, off);
  if (lane == 0) R[256 + (long)node * 512] = sigm(s + lin_b[0]);
}

// ---------------- pred[e] = score[src] * score[dst] -------------------------
__global__ void pred_kernel(const int* __restrict__ eli, const float* __restrict__ R,
                            float* __restrict__ out) {
  int e = blockIdx.x * 256 + threadIdx.x;
  if (e < EE) {
    int a = eli[e];       a = (unsigned)a < NN ? a : 0;
    int b = eli[EE + e];  b = (unsigned)b < NN ? b : 0;
    out[e] = R[256 + (long)a * 512] * R[256 + (long)b * 512];
  }
}

// ---------------- out2 = hn @ skip_w.T + skip_b (in-place-safe MFMA) --------
__launch_bounds__(256)
__global__ void out2_kernel(const unsigned short* __restrict__ hnb,
                            const float* __restrict__ skip_w,
                            const float* __restrict__ skip_b,
                            float* __restrict__ out2) {
  __shared__ unsigned short Asl[32][520];
  __shared__ unsigned short Bsl[512][40];
  const int tid = threadIdx.x;
  const int lane = tid & 63, wv = tid >> 6;
  const int r = lane & 15, q = lane >> 4;
  const int m0 = blockIdx.x * 32;

  {
    int arow = tid >> 4;
    int acol = (tid & 15) * 32;
    #pragma unroll
    for (int hh = 0; hh < 2; ++hh) {
      int grow = m0 + hh * 16 + arow;
      unsigned short* dst = &Asl[hh * 16 + arow][acol];
      if (grow < NN) {
        const unsigned short* hr = hnb + (long)grow * 1024 + acol;
        *(int4*)(dst)      = *(const int4*)(hr);
        *(int4*)(dst + 8)  = *(const int4*)(hr + 8);
        *(int4*)(dst + 16) = *(const int4*)(hr + 16);
        *(int4*)(dst + 24) = *(const int4*)(hr + 24);
      } else {
        int4 z = {0, 0, 0, 0};
        *(int4*)(dst) = z; *(int4*)(dst + 8) = z;
        *(int4*)(dst + 16) = z; *(int4*)(dst + 24) = z;
      }
    }
  }

  const f32x4 fzero = {0.f, 0.f, 0.f, 0.f};
  f32x4 acc[2][8];
  #pragma unroll
  for (int rg = 0; rg < 2; ++rg)
    #pragma unroll
    for (int i = 0; i < 8; ++i) acc[rg][i] = fzero;

  const int ksub = (tid & 3) * 8;
  const int jb = tid >> 2;

  for (int k0 = 0; k0 < H; k0 += 32) {
    __syncthreads();
    #pragma unroll
    for (int it = 0; it < 8; ++it) {
      int jj = it * 64 + jb;
      const float* src = skip_w + (long)jj * H + k0 + ksub;
      cvt_store8(&Bsl[jj][ksub], *(const float4*)src, *(const float4*)(src + 4));
    }
    __syncthreads();
    bf16x8 af0 = *(const bf16x8*)&Asl[r][k0 + q * 8];
    bf16x8 af1 = *(const bf16x8*)&Asl[16 + r][k0 + q * 8];
    #pragma unroll
    for (int i = 0; i < 8; ++i) {
      bf16x8 bf = *(const bf16x8*)&Bsl[(wv * 8 + i) * 16 + r][q * 8];
      acc[0][i] = __builtin_amdgcn_mfma_f32_16x16x32_bf16(af0, bf, acc[0][i], 0, 0, 0);
      acc[1][i] = __builtin_amdgcn_mfma_f32_16x16x32_bf16(af1, bf, acc[1][i], 0, 0, 0);
    }
  }
  #pragma unroll
  for (int rg = 0; rg < 2; ++rg)
    #pragma unroll
    for (int i = 0; i < 8; ++i) {
      int col = (wv * 8 + i) * 16 + r;
      float sbv = skip_b[col];
      #pragma unroll
      for (int g = 0; g < 4; ++g) {
        int grow = m0 + rg * 16 + q * 4 + g;
        if (grow < NN) out2[(long)grow * H + col] = acc[rg][i][g] + sbv;
      }
    }
}

// ---------------- host launcher (d_ws is UNUSABLE in this harness) ----------
extern "C" void kernel_launch(void* const* d_in, const int* in_sizes, int n_in,
                              void* d_out, int out_size, void* d_ws, size_t ws_size,
                              hipStream_t stream) {
  const float* emb    = (const float*)d_in[0];
  const float* W_ir   = (const float*)d_in[1];
  const float* b_ir   = (const float*)d_in[2];
  const float* W_iz   = (const float*)d_in[3];
  const float* b_iz   = (const float*)d_in[4];
  const float* lin_w  = (const float*)d_in[5];
  const float* lin_b  = (const float*)d_in[6];
  const float* skip_w = (const float*)d_in[7];
  const float* skip_b = (const float*)d_in[8];
  const int*   walk   = (const int*)d_in[9];
  const int*   eli    = (const int*)d_in[10];
  float* out = (float*)d_out;
  float* R   = out + EE;                           // out2 region: NN x H f32
  unsigned short* hnb = (unsigned short*)R;        // bf16 hn inside out2 slots

  dim3 g1(16, 48);
  gru_fused<<<g1, 256, 0, stream>>>(emb, W_ir, W_iz, b_ir, b_iz, walk, hnb);
  score_kernel<<<2500, 256, 0, stream>>>(hnb, lin_w, lin_b, R);
  pred_kernel<<<391, 256, 0, stream>>>(eli, R, out);        // before out2 (slots reused)
  out2_kernel<<<313, 256, 0, stream>>>(hnb, skip_w, skip_b, R);
}